// Round 1
// baseline (4958265.234 us; speedup 1.0000x reference)
//
#include <hip/hip_runtime.h>
#include <stdint.h>

#define NITEMS 50000
#define SEQ    200
#define TMAX   199

typedef int v4i __attribute__((ext_vector_type(4)));

// ws layout:
//   [0,     8192): handshake: 64 groups * 32 ints (xcc ids / L2 probe / decision)
//   [8192,  8200): accum {nll_sum, cnt}
//   [16384, 16384 + 64*2*256*8): tagged h pairs: (group, parity slot, 256) x {u32 tag, f32 h}

template<int CTRL>
__device__ __forceinline__ float dpp_add(float x) {
    int r = __builtin_amdgcn_update_dpp(0, __float_as_int(x), CTRL, 0xF, 0xF, true);
    return x + __int_as_float(r);
}

// ---------------- tagged-pair exchange primitives ----------------
// Pair = {u32 step_tag, f32 value}: one aligned dwordx2 => tag travels atomically
// with the data, so a single load both detects readiness and delivers h.
// L2 path (same-XCD): sc0 = bypass L1, served by the XCD's shared L2 (~200cy).
// DEV path (fallback): sc0 sc1 = bypass L1+L2, served at the Infinity Cache
// (device coherence point) — same semantics the old agent-scope atomics had.
// buffer_inv in the retry path guarantees forward progress even if the sc-bit
// bypass semantics differ from expectation (invalidate, then re-fetch).

#define LD8_BODY(SCOPE)                                                     \
    asm volatile(                                                           \
        "global_load_dwordx4 %0, %8, off " SCOPE "\n\t"                     \
        "global_load_dwordx4 %1, %8, off offset:16 " SCOPE "\n\t"           \
        "global_load_dwordx4 %2, %8, off offset:32 " SCOPE "\n\t"           \
        "global_load_dwordx4 %3, %8, off offset:48 " SCOPE "\n\t"           \
        "global_load_dwordx4 %4, %8, off offset:64 " SCOPE "\n\t"           \
        "global_load_dwordx4 %5, %8, off offset:80 " SCOPE "\n\t"           \
        "global_load_dwordx4 %6, %8, off offset:96 " SCOPE "\n\t"           \
        "global_load_dwordx4 %7, %8, off offset:112 " SCOPE "\n\t"          \
        "s_waitcnt vmcnt(0)"                                                \
        : "=&v"(a0), "=&v"(a1), "=&v"(a2), "=&v"(a3),                       \
          "=&v"(a4), "=&v"(a5), "=&v"(a6), "=&v"(a7)                        \
        : "v"(p) : "memory")

__device__ __forceinline__ void ld8_l2(const uint2* p, v4i& a0, v4i& a1, v4i& a2, v4i& a3,
                                       v4i& a4, v4i& a5, v4i& a6, v4i& a7) { LD8_BODY("sc0"); }
__device__ __forceinline__ void ld8_dev(const uint2* p, v4i& a0, v4i& a1, v4i& a2, v4i& a3,
                                        v4i& a4, v4i& a5, v4i& a6, v4i& a7) { LD8_BODY("sc0 sc1"); }

#define LD2_BODY(SCOPE)                                                     \
    asm volatile(                                                           \
        "global_load_dwordx4 %0, %2, off " SCOPE "\n\t"                     \
        "global_load_dwordx4 %1, %2, off offset:16 " SCOPE "\n\t"           \
        "s_waitcnt vmcnt(0)"                                                \
        : "=&v"(e0), "=&v"(e1) : "v"(p) : "memory")

__device__ __forceinline__ void ld2_l2(const uint2* p, v4i& e0, v4i& e1)  { LD2_BODY("sc0"); }
__device__ __forceinline__ void ld2_dev(const uint2* p, v4i& e0, v4i& e1) { LD2_BODY("sc0 sc1"); }

__device__ __forceinline__ void st_pair_l2(uint2* p, unsigned long long v) {
    asm volatile("global_store_dwordx2 %0, %1, off sc0" :: "v"(p), "v"(v) : "memory");
}
__device__ __forceinline__ void st_pair_dev(uint2* p, unsigned long long v) {
    asm volatile("global_store_dwordx2 %0, %1, off sc0 sc1" :: "v"(p), "v"(v) : "memory");
}
__device__ __forceinline__ void inv_l1()   { asm volatile("buffer_inv sc0" ::: "memory"); }
__device__ __forceinline__ void inv_l1l2() { asm volatile("buffer_inv sc0 sc1" ::: "memory"); }

__global__ __launch_bounds__(512, 2)
void lstm_main(const int* __restrict__ items, const int* __restrict__ actions,
               const float* __restrict__ WihT, const float* __restrict__ Whh,
               const float* __restrict__ b_lstm, const float* __restrict__ trans_emb,
               const float* __restrict__ Wq, const float* __restrict__ bq,
               int* hs, uint2* pairs, float* accum)
{
    const int bid  = blockIdx.x;
    // XCD-locality: group's 4 blocks share bid%8 (same XCD under round-robin).
    // Correctness no longer assumes this — the handshake verifies it.
    const int g    = (bid & 7) + 8 * ((bid >> 3) >> 2);   // batch/group 0..63
    const int q    = (bid >> 3) & 3;                      // quarter 0..3
    const int tid  = threadIdx.x;
    const int lane = tid & 63;
    const int wv   = tid >> 6;
    const int rg   = tid >> 4;    // 0..31 rowgroup (8 rows each)
    const int kc   = tid & 15;    // 0..15 k-chunk (16 k each)

    __shared__ float xp_lds[2][256];
    __shared__ float gate_lds[2][256];   // double-buffered: lets us drop barrier B2
    __shared__ float b_lds[256];
    __shared__ float emb_lds[2][256];
    __shared__ float wq_lds[2][256];
    __shared__ float bq_lds[2];
    __shared__ int   items_s[SEQ];
    __shared__ int   act_s[SEQ];
    __shared__ int   len_sh;
    __shared__ int   use_l2_sh;

    // ---------------- prologue ----------------
    for (int i = tid; i < SEQ; i += 512) {
        items_s[i] = items[g * SEQ + i];
        act_s[i]   = actions[g * SEQ + i];
    }
    if (tid < 256) {
        b_lds[tid] = b_lstm[(tid >> 6) * 256 + q * 64 + (tid & 63)];
    } else {
        const int k = tid - 256;
        wq_lds[0][k] = Wq[k];
        wq_lds[1][k] = Wq[256 + k];
    }
    if (tid == 0) { bq_lds[0] = bq[0]; bq_lds[1] = bq[1]; }

    // Whh slice into registers (overlaps with the handshake below):
    // thread (rg,kc) holds rows rg*8..+8, k in [16*kc,16*kc+16)
    float wgt[8][16];
    #pragma unroll
    for (int r = 0; r < 8; ++r) {
        const int r_blk = rg * 8 + r;                               // 0..255
        const int j = (r_blk >> 6) * 256 + q * 64 + (r_blk & 63);   // global gate row
        const float4* wp = (const float4*)(Whh + (size_t)j * 256 + kc * 16);
        #pragma unroll
        for (int m = 0; m < 4; ++m) {
            float4 v = wp[m];
            wgt[r][4*m+0] = v.x; wgt[r][4*m+1] = v.y;
            wgt[r][4*m+2] = v.z; wgt[r][4*m+3] = v.w;
        }
    }
    __syncthreads();

    if (tid == 0) {
        int Lx = 0;
        while (Lx < SEQ && items_s[Lx] != 0) ++Lx;   // valid region is a prefix
        len_sh = Lx;

        // ---- same-XCD handshake ----
        int* hsg = hs + g * 32;
        int xcc;
        asm volatile("s_getreg_b32 %0, hwreg(HW_REG_XCC_ID)" : "=s"(xcc));
        xcc &= 0xF;
        // 1. probe token through the L2 path, completed before the agent publish
        asm volatile("global_store_dword %0, %1, off sc0\n\t"
                     "s_waitcnt vmcnt(0)" :: "v"(hsg + 8 + q), "v"(1) : "memory");
        // 2. publish xcc (nonzero-marked), agent scope (always correct)
        __hip_atomic_store(hsg + q, xcc | 0x10, __ATOMIC_RELEASE, __HIP_MEMORY_SCOPE_AGENT);
        // 3. gather all xccs (peers have stored their probe token before this succeeds)
        int xs[4];
        for (int p = 0; p < 4; ++p) {
            int v = 0, guard = 0;
            do {
                v = __hip_atomic_load(hsg + p, __ATOMIC_ACQUIRE, __HIP_MEMORY_SCOPE_AGENT);
                if (v) break;
                __builtin_amdgcn_s_sleep(2);
            } while (++guard < (1 << 20));
            xs[p] = v;
        }
        int ok = (xs[0] == xs[1]) & (xs[1] == xs[2]) & (xs[2] == xs[3]) & (xs[0] != 0);
        // 4. verify peers' tokens are visible through the L2 path (empirical probe)
        if (ok) {
            for (int p = 0; p < 4 && ok; ++p) {
                if (p == q) continue;
                int guard = 0;
                for (;;) {
                    int v;
                    asm volatile("global_load_dword %0, %1, off sc0\n\t"
                                 "s_waitcnt vmcnt(0)"
                                 : "=&v"(v) : "v"(hsg + 8 + p) : "memory");
                    if (v == 1) break;
                    if (++guard > 4096) { ok = 0; break; }
                    inv_l1();
                }
            }
        }
        // 5. agree on the decision via agent scope (all 4 must use the same path)
        __hip_atomic_store(hsg + 16 + q, ok ? 1 : 2, __ATOMIC_RELEASE, __HIP_MEMORY_SCOPE_AGENT);
        int all_ok = 1;
        for (int p = 0; p < 4; ++p) {
            int v = 0, guard = 0;
            do {
                v = __hip_atomic_load(hsg + 16 + p, __ATOMIC_ACQUIRE, __HIP_MEMORY_SCOPE_AGENT);
                if (v) break;
                __builtin_amdgcn_s_sleep(2);
            } while (++guard < (1 << 20));
            all_ok &= (v == 1);
        }
        use_l2_sh = all_ok;
    }
    __syncthreads();
    const int  len    = len_sh;           // 100..200
    const int  L      = min(len, TMAX);   // LSTM steps
    const bool use_l2 = (use_l2_sh != 0);

    // stage x_proj for tokens 0 and 1 (xp prefetch runs 2 tokens ahead in the loop)
    if (wv == 0) {
        const int it = items_s[0], ac = act_s[0];
        const int c = lane >> 4, off = (lane & 15) * 4;
        float4 va = *(const float4*)(WihT + (size_t)it * 1024 + c * 256 + q * 64 + off);
        float4 vb = *(const float4*)(WihT + (size_t)(NITEMS + ac) * 1024 + c * 256 + q * 64 + off);
        *(float4*)&xp_lds[0][c * 64 + off] =
            make_float4(va.x+vb.x, va.y+vb.y, va.z+vb.z, va.w+vb.w);
    } else if (wv == 1 && L > 1) {
        const int it = items_s[1], ac = act_s[1];
        const int c = lane >> 4, off = (lane & 15) * 4;
        float4 va = *(const float4*)(WihT + (size_t)it * 1024 + c * 256 + q * 64 + off);
        float4 vb = *(const float4*)(WihT + (size_t)(NITEMS + ac) * 1024 + c * 256 + q * 64 + off);
        *(float4*)&xp_lds[1][c * 64 + off] =
            make_float4(va.x+vb.x, va.y+vb.y, va.z+vb.z, va.w+vb.w);
    }
    // stage emb for query token 0 (q_it = items[1])
    if (q == 0 && wv == 2) {
        const int qe = items_s[1];
        float4 e = make_float4(0.f,0.f,0.f,0.f);
        if (qe != 0) e = *(const float4*)(trans_emb + (size_t)qe * 256 + 4 * lane);
        *(float4*)&emb_lds[0][4 * lane] = e;
    }
    __syncthreads();

    float c_cell = 0.f;                 // used by tid<64 only
    float nll_acc = 0.f, cnt_acc = 0.f; // used by wave2/q0 lane0 only
    float hreg[16];
    #pragma unroll
    for (int m = 0; m < 16; ++m) hreg[m] = 0.f;

    uint2* gbuf = pairs + (size_t)g * 512;   // [parity][256] pairs

    for (int t = 0; t < L; ++t) {
        // ---- stage 1: acquire h^t — each thread polls its own tagged pairs.
        // Single L2 round trip both detects readiness (tag==t) and delivers h.
        if (t > 0) {
            const uint2* src = gbuf + ((t & 1) * 256 + kc * 16);
            v4i a0, a1, a2, a3, a4, a5, a6, a7;
            int guard = 0;
            for (;;) {
                if (use_l2) ld8_l2(src, a0,a1,a2,a3,a4,a5,a6,a7);
                else        ld8_dev(src, a0,a1,a2,a3,a4,a5,a6,a7);
                int ok = (a0.x==t)&(a0.z==t)&(a1.x==t)&(a1.z==t)
                       & (a2.x==t)&(a2.z==t)&(a3.x==t)&(a3.z==t)
                       & (a4.x==t)&(a4.z==t)&(a5.x==t)&(a5.z==t)
                       & (a6.x==t)&(a6.z==t)&(a7.x==t)&(a7.z==t);
                if (ok) break;
                if (++guard > (1 << 14)) break;   // bounded: never hang
                if (use_l2) inv_l1(); else inv_l1l2();
            }
            hreg[ 0]=__int_as_float(a0.y); hreg[ 1]=__int_as_float(a0.w);
            hreg[ 2]=__int_as_float(a1.y); hreg[ 3]=__int_as_float(a1.w);
            hreg[ 4]=__int_as_float(a2.y); hreg[ 5]=__int_as_float(a2.w);
            hreg[ 6]=__int_as_float(a3.y); hreg[ 7]=__int_as_float(a3.w);
            hreg[ 8]=__int_as_float(a4.y); hreg[ 9]=__int_as_float(a4.w);
            hreg[10]=__int_as_float(a5.y); hreg[11]=__int_as_float(a5.w);
            hreg[12]=__int_as_float(a6.y); hreg[13]=__int_as_float(a6.w);
            hreg[14]=__int_as_float(a7.y); hreg[15]=__int_as_float(a7.w);
        }

        // ---- early issues (consumed at stage 4; hides HBM latency) ----
        const int tn2 = t + 2;
        float4 xa = make_float4(0,0,0,0), xb = make_float4(0,0,0,0);
        float4 ev = make_float4(0,0,0,0);
        float  he[4] = {0,0,0,0};
        if (wv == 1 && tn2 < L) {           // x_proj prefetch, 2 tokens ahead
            const int it = items_s[tn2], ac = act_s[tn2];
            const int c = lane >> 4, off = (lane & 15) * 4;
            xa = *(const float4*)(WihT + (size_t)it * 1024 + c * 256 + q * 64 + off);
            xb = *(const float4*)(WihT + (size_t)(NITEMS + ac) * 1024 + c * 256 + q * 64 + off);
        }
        if (q == 0 && wv == 2) {
            // he poll FIRST (vmcnt(0) inside must not wait on the ev HBM gather)
            if (t >= 1) {
                const uint2* src2 = gbuf + ((t & 1) * 256 + lane * 4);
                v4i e0, e1; int guard = 0;
                for (;;) {
                    if (use_l2) ld2_l2(src2, e0, e1);
                    else        ld2_dev(src2, e0, e1);
                    int ok = (e0.x==t)&(e0.z==t)&(e1.x==t)&(e1.z==t);
                    if (ok) break;
                    if (++guard > (1 << 14)) break;
                    if (use_l2) inv_l1(); else inv_l1l2();
                }
                he[0]=__int_as_float(e0.y); he[1]=__int_as_float(e0.w);
                he[2]=__int_as_float(e1.y); he[3]=__int_as_float(e1.w);
            }
            const int qe = items_s[t + 1];   // emb for query token t
            if (qe != 0) ev = *(const float4*)(trans_emb + (size_t)qe * 256 + 4 * lane);
        }

        // ---- stage 2: partial dot products (weights in regs) ----
        float acc[8];
        #pragma unroll
        for (int r = 0; r < 8; ++r) acc[r] = 0.f;
        #pragma unroll
        for (int m = 0; m < 16; ++m) {
            #pragma unroll
            for (int r = 0; r < 8; ++r) acc[r] = fmaf(wgt[r][m], hreg[m], acc[r]);
        }
        // ---- stage 3: 16-lane reduce over kc via DPP row rotations ----
        #pragma unroll
        for (int r = 0; r < 8; ++r) {
            float v = acc[r];
            v = dpp_add<0x128>(v);   // row_ror:8
            v = dpp_add<0x124>(v);   // row_ror:4
            v = dpp_add<0x122>(v);   // row_ror:2
            v = dpp_add<0x121>(v);   // row_ror:1
            acc[r] = v;
        }
        if (kc == 0) {
            #pragma unroll
            for (int r = 0; r < 8; ++r) {
                const int r_blk = rg * 8 + r;
                gate_lds[t & 1][r_blk] = acc[r] + xp_lds[t & 1][r_blk] + b_lds[r_blk];
            }
        }
        __syncthreads();   // B1 (the only barrier per step)

        // ---- stage 4: per-wave roles ----
        if (tid < 64) {
            const int d = tid;
            float gi = gate_lds[t & 1][d];
            float gf = gate_lds[t & 1][64 + d];
            float gg = gate_lds[t & 1][128 + d];
            float go = gate_lds[t & 1][192 + d];
            float ii = 1.f / (1.f + __expf(-gi));
            float ff = 1.f / (1.f + __expf(-gf));
            float oo = 1.f / (1.f + __expf(-go));
            float gt = tanhf(gg);
            c_cell = ff * c_cell + ii * gt;
            float hn = oo * tanhf(c_cell);
            unsigned long long pv = (unsigned long long)(unsigned)(t + 1)
                                  | ((unsigned long long)__float_as_uint(hn) << 32);
            uint2* dst = gbuf + (((t + 1) & 1) * 256 + q * 64 + d);
            if (use_l2) st_pair_l2(dst, pv); else st_pair_dev(dst, pv);
        } else if (wv == 1) {
            if (tn2 < L) {   // slot (tn2&1)==(t&1): all readers of token t finished pre-B1
                const int c = lane >> 4, off = (lane & 15) * 4;
                *(float4*)&xp_lds[tn2 & 1][c * 64 + off] =
                    make_float4(xa.x+xb.x, xa.y+xb.y, xa.z+xb.z, xa.w+xb.w);
            }
        } else if (wv == 2 && q == 0) {
            if (t >= 1) {   // query for token t-1; always valid since t < L <= len
                const float* eb = &emb_lds[(t - 1) & 1][0];
                float s0 = 0.f, s1 = 0.f;
                #pragma unroll
                for (int m = 0; m < 4; ++m) {
                    const int k = 4 * lane + m;
                    float p = eb[k] * he[m];
                    s0 = fmaf(p, wq_lds[0][k], s0);
                    s1 = fmaf(p, wq_lds[1][k], s1);
                }
                #pragma unroll
                for (int off2 = 32; off2; off2 >>= 1) {
                    s0 += __shfl_xor(s0, off2);
                    s1 += __shfl_xor(s1, off2);
                }
                if (lane == 0) {
                    const int tgt = act_s[t];     // actions[b, (t-1)+1]
                    float z0 = s0 + bq_lds[0], z1 = s1 + bq_lds[1];
                    float mz = fmaxf(z0, z1);
                    float lse = mz + __logf(__expf(z0 - mz) + __expf(z1 - mz));
                    nll_acc += lse - (tgt ? z1 : z0);
                    cnt_acc += 1.f;
                }
            }
            *(float4*)&emb_lds[t & 1][4 * lane] = ev;   // stage emb for query token t
        }
        // no B2: gate_lds double-buffered; xp/emb hazards ordered by the tag
        // protocol (a tag t+2 store implies its wave passed B1(t+1)).
    }

    // ---- final token (t = L-1 uses h^L); valid only when len==200 ----
    if (q == 0 && wv == 2) {
        if (items_s[L] != 0) {
            const uint2* src2 = gbuf + ((L & 1) * 256 + lane * 4);
            v4i e0, e1; int guard = 0;
            for (;;) {
                if (use_l2) ld2_l2(src2, e0, e1);
                else        ld2_dev(src2, e0, e1);
                int ok = (e0.x==L)&(e0.z==L)&(e1.x==L)&(e1.z==L);
                if (ok) break;
                if (++guard > (1 << 14)) break;
                if (use_l2) inv_l1(); else inv_l1l2();
            }
            float he2[4] = { __int_as_float(e0.y), __int_as_float(e0.w),
                             __int_as_float(e1.y), __int_as_float(e1.w) };
            const float* eb = &emb_lds[(L - 1) & 1][0];
            float s0 = 0.f, s1 = 0.f;
            #pragma unroll
            for (int m = 0; m < 4; ++m) {
                const int k = 4 * lane + m;
                float p = eb[k] * he2[m];
                s0 = fmaf(p, wq_lds[0][k], s0);
                s1 = fmaf(p, wq_lds[1][k], s1);
            }
            #pragma unroll
            for (int off2 = 32; off2; off2 >>= 1) {
                s0 += __shfl_xor(s0, off2);
                s1 += __shfl_xor(s1, off2);
            }
            if (lane == 0) {
                const int tgt = act_s[L];
                float z0 = s0 + bq_lds[0], z1 = s1 + bq_lds[1];
                float mz = fmaxf(z0, z1);
                float lse = mz + __logf(__expf(z0 - mz) + __expf(z1 - mz));
                nll_acc += lse - (tgt ? z1 : z0);
                cnt_acc += 1.f;
            }
        }
        if (lane == 0) {
            atomicAdd(&accum[0], nll_acc);
            atomicAdd(&accum[1], cnt_acc);
        }
    }
}

__global__ void finalize_k(const float* __restrict__ accum, float* __restrict__ out) {
    out[0] = accum[0] / accum[1];
}

extern "C" void kernel_launch(void* const* d_in, const int* in_sizes, int n_in,
                              void* d_out, int out_size, void* d_ws, size_t ws_size,
                              hipStream_t stream)
{
    const int*   items     = (const int*)d_in[0];
    const int*   actions   = (const int*)d_in[1];
    const float* WihT      = (const float*)d_in[2];
    const float* Whh       = (const float*)d_in[3];
    const float* b_lstm    = (const float*)d_in[4];
    const float* trans_emb = (const float*)d_in[5];
    const float* Wq        = (const float*)d_in[6];
    const float* bq        = (const float*)d_in[7];

    char*  ws    = (char*)d_ws;
    int*   hs    = (int*)ws;                   // 8192 B handshake
    float* accum = (float*)(ws + 8192);        // 8 B
    uint2* pairs = (uint2*)(ws + 16384);       // 64*2*256*8 = 262144 B

    hipMemsetAsync(d_ws, 0, 16384 + 64 * 2 * 256 * 8, stream);

    lstm_main<<<dim3(256), dim3(512), 0, stream>>>(
        items, actions, WihT, Whh, b_lstm, trans_emb, Wq, bq, hs, pairs, accum);
    finalize_k<<<dim3(1), dim3(1), 0, stream>>>(accum, (float*)d_out);
}

// Round 3
// 1594.122 us; speedup vs baseline: 3110.3425x; 3110.3425x over previous
//
#include <hip/hip_runtime.h>
#include <stdint.h>

#define NITEMS 50000
#define SEQ    200
#define TMAX   199

typedef unsigned long long u64;

// ws layout:
//   [8192,  8200): accum {nll_sum, cnt}
//   [16384, 16384 + 64*2*256*8): tagged h pairs per group:
//       pair = {u32 step_tag (low), f32 h bits (high)} — one aligned 8B unit,
//       exchanged with compiler-generated agent-scope relaxed atomics (the
//       primitive the 1136us baseline already used for its h payload).
//       One load = detect (tag==t) + deliver (h bits). No flags, no sleeps,
//       no cache-bit asm, no invalidates.

template<int CTRL>
__device__ __forceinline__ float dpp_add(float x) {
    int r = __builtin_amdgcn_update_dpp(0, __float_as_int(x), CTRL, 0xF, 0xF, true);
    return x + __int_as_float(r);
}

__device__ __forceinline__ u64 ld_pair(const u64* p) {
    return __hip_atomic_load(p, __ATOMIC_RELAXED, __HIP_MEMORY_SCOPE_AGENT);
}
__device__ __forceinline__ void st_pair(u64* p, u64 v) {
    __hip_atomic_store(p, v, __ATOMIC_RELAXED, __HIP_MEMORY_SCOPE_AGENT);
}
// Barrier that drains LDS only (lgkmcnt), NOT vmem: h-store visibility is the
// tag protocol's job; draining vmcnt(0) here (as __syncthreads would) adds the
// store's L3 latency to every step. "memory" clobber pins compiler ordering.
__device__ __forceinline__ void step_barrier() {
    asm volatile("s_waitcnt lgkmcnt(0)\n\ts_barrier" ::: "memory");
}

__global__ __launch_bounds__(512, 1)   // grid == 256 == #CUs -> 1 block/CU anyway.
                                       // min-waves 1 -> VGPR cap 256 -> wgt[8][16]
                                       // (128 floats) lives in VGPRs, not AGPRs
                                       // (round-0's 116-VGPR build paid an
                                       //  accvgpr move per FMA).
void lstm_main(const int* __restrict__ items, const int* __restrict__ actions,
               const float* __restrict__ WihT, const float* __restrict__ Whh,
               const float* __restrict__ b_lstm, const float* __restrict__ trans_emb,
               const float* __restrict__ Wq, const float* __restrict__ bq,
               u64* pairs, float* accum)
{
    const int bid  = blockIdx.x;
    // XCD-locality heuristic only (perf, not correctness): group's 4 blocks
    // share bid%8, which round-robin dispatch maps to one XCD.
    const int g    = (bid & 7) + 8 * ((bid >> 3) >> 2);   // batch/group 0..63
    const int q    = (bid >> 3) & 3;                      // quarter 0..3
    const int tid  = threadIdx.x;
    const int lane = tid & 63;
    const int wv   = tid >> 6;
    const int rg   = tid >> 4;    // 0..31 rowgroup
    const int kc   = tid & 15;    // 0..15 k-chunk (16 k each)

    __shared__ float xp_lds[3][256];     // triple-buffered: write t+2, read t,
                                         // with only ONE barrier per step
    __shared__ float b_lds[256];
    __shared__ float emb_lds[2][256];
    __shared__ float wq_lds[2][256];
    __shared__ float bq_lds[2];
    __shared__ int   items_s[SEQ];
    __shared__ int   act_s[SEQ];
    __shared__ int   len_sh;

    // ---------------- prologue ----------------
    for (int i = tid; i < SEQ; i += 512) {
        items_s[i] = items[g * SEQ + i];
        act_s[i]   = actions[g * SEQ + i];
    }
    if (tid < 256) {
        b_lds[tid] = b_lstm[(tid >> 6) * 256 + q * 64 + (tid & 63)];
    } else {
        const int k = tid - 256;
        wq_lds[0][k] = Wq[k];
        wq_lds[1][k] = Wq[256 + k];
    }
    if (tid == 0) { bq_lds[0] = bq[0]; bq_lds[1] = bq[1]; }

    // Whh ownership (fused-activation layout): thread (rg,kc) owns the 8 rows
    // {gt*256 + q*64 + 2*rg + e : gt=0..3, e=0..1}, k in [16kc, 16kc+16).
    // After the kc-reduce, kc==0 lanes hold i,f,g,o for dims 2rg, 2rg+1 and can
    // compute c,h and store tagged h DIRECTLY — no LDS gate hop, no mid-step
    // barrier, no dedicated activation wave.
    float wgt[8][16];
    #pragma unroll
    for (int gt = 0; gt < 4; ++gt) {
        #pragma unroll
        for (int e = 0; e < 2; ++e) {
            const int j = gt * 256 + q * 64 + 2 * rg + e;   // global gate row
            const float4* wp = (const float4*)(Whh + (size_t)j * 256 + kc * 16);
            #pragma unroll
            for (int m2 = 0; m2 < 4; ++m2) {
                float4 v = wp[m2];
                wgt[gt*2+e][4*m2+0] = v.x; wgt[gt*2+e][4*m2+1] = v.y;
                wgt[gt*2+e][4*m2+2] = v.z; wgt[gt*2+e][4*m2+3] = v.w;
            }
        }
    }
    __syncthreads();

    if (tid == 0) {
        int Lx = 0;
        while (Lx < SEQ && items_s[Lx] != 0) ++Lx;   // valid region is a prefix
        len_sh = Lx;
    }
    // stage x_proj for tokens 0 and 1 (in-loop prefetch stages token t+2)
    if (wv == 0) {
        const int it = items_s[0], ac = act_s[0];
        const int c = lane >> 4, off = (lane & 15) * 4;
        float4 va = *(const float4*)(WihT + (size_t)it * 1024 + c * 256 + q * 64 + off);
        float4 vb = *(const float4*)(WihT + (size_t)(NITEMS + ac) * 1024 + c * 256 + q * 64 + off);
        *(float4*)&xp_lds[0][c * 64 + off] =
            make_float4(va.x+vb.x, va.y+vb.y, va.z+vb.z, va.w+vb.w);
    } else if (wv == 1) {
        const int it = items_s[1], ac = act_s[1];
        const int c = lane >> 4, off = (lane & 15) * 4;
        float4 va = *(const float4*)(WihT + (size_t)it * 1024 + c * 256 + q * 64 + off);
        float4 vb = *(const float4*)(WihT + (size_t)(NITEMS + ac) * 1024 + c * 256 + q * 64 + off);
        *(float4*)&xp_lds[1][c * 64 + off] =
            make_float4(va.x+vb.x, va.y+vb.y, va.z+vb.z, va.w+vb.w);
    }
    __syncthreads();
    const int len = len_sh;           // 100..200
    const int L   = min(len, TMAX);   // LSTM steps

    float c0 = 0.f, c1 = 0.f;           // cell state, kc==0 threads, dims 2rg, 2rg+1
    float nll_acc = 0.f, cnt_acc = 0.f; // wave2/q0 lane0 only
    float hreg[16];
    #pragma unroll
    for (int m = 0; m < 16; ++m) hreg[m] = 0.f;

    u64* gbuf = pairs + (size_t)g * 512;   // [parity][256] tagged pairs

    for (int t = 0; t < L; ++t) {
        const int xs = t % 3;          // xp read slot
        // ---- stage 1: acquire h^t — each thread polls its own 16 tagged pairs.
        // One agent-scope trip both detects readiness (tag==t) and delivers h.
        if (t > 0) {
            const u64* src = gbuf + (t & 1) * 256 + kc * 16;
            u64 v[16];
            int guard = 0;
            for (;;) {
                #pragma unroll
                for (int m = 0; m < 16; ++m) v[m] = ld_pair(src + m);
                unsigned ok = 1u;
                #pragma unroll
                for (int m = 0; m < 16; ++m) ok &= (unsigned)((unsigned)v[m] == (unsigned)t);
                if (ok || ++guard > (1 << 16)) break;    // bounded: never hang
            }
            #pragma unroll
            for (int m = 0; m < 16; ++m)
                hreg[m] = __uint_as_float((unsigned)(v[m] >> 32));
        }

        // ---- stage 2: prefetch issues (after poll so their vmcnt waits don't
        // land inside the poll loop; HBM latency hides under dot+reduce) ----
        const int tn2 = t + 2;
        float4 xa = make_float4(0,0,0,0), xb = make_float4(0,0,0,0);
        float4 ev = make_float4(0,0,0,0);
        if (wv == 1 && tn2 < L) {           // x_proj for token t+2
            const int it = items_s[tn2], ac = act_s[tn2];
            const int c = lane >> 4, off = (lane & 15) * 4;
            xa = *(const float4*)(WihT + (size_t)it * 1024 + c * 256 + q * 64 + off);
            xb = *(const float4*)(WihT + (size_t)(NITEMS + ac) * 1024 + c * 256 + q * 64 + off);
        }
        if (q == 0 && wv == 2) {
            const int qe = items_s[t + 1];   // emb for query token t
            if (qe != 0) ev = *(const float4*)(trans_emb + (size_t)qe * 256 + 4 * lane);
        }

        // ---- stage 3: partial dot products (weights in regs) ----
        float acc[8];
        #pragma unroll
        for (int r = 0; r < 8; ++r) acc[r] = 0.f;
        #pragma unroll
        for (int m = 0; m < 16; ++m) {
            #pragma unroll
            for (int r = 0; r < 8; ++r) acc[r] = fmaf(wgt[r][m], hreg[m], acc[r]);
        }
        // 16-lane reduce over kc via DPP row rotations (all 16 lanes get sums)
        #pragma unroll
        for (int r = 0; r < 8; ++r) {
            float v = acc[r];
            v = dpp_add<0x128>(v);   // row_ror:8
            v = dpp_add<0x124>(v);   // row_ror:4
            v = dpp_add<0x122>(v);   // row_ror:2
            v = dpp_add<0x121>(v);   // row_ror:1
            acc[r] = v;
        }

        // ---- stage 4: fused activations + tagged h store (kc==0 lanes) ----
        if (kc == 0) {
            #pragma unroll
            for (int e = 0; e < 2; ++e) {
                const int d = 2 * rg + e;                 // dim within quarter
                float gi = acc[0 + e] + xp_lds[xs][      d] + b_lds[      d];
                float gf = acc[2 + e] + xp_lds[xs][ 64 + d] + b_lds[ 64 + d];
                float gg = acc[4 + e] + xp_lds[xs][128 + d] + b_lds[128 + d];
                float go = acc[6 + e] + xp_lds[xs][192 + d] + b_lds[192 + d];
                float ii = 1.f / (1.f + __expf(-gi));
                float ff = 1.f / (1.f + __expf(-gf));
                float oo = 1.f / (1.f + __expf(-go));
                float gv = tanhf(gg);
                float cn = ff * (e ? c1 : c0) + ii * gv;
                if (e) c1 = cn; else c0 = cn;
                float hn = oo * tanhf(cn);
                u64 pv = (u64)(unsigned)(t + 1) | ((u64)__float_as_uint(hn) << 32);
                st_pair(gbuf + ((t + 1) & 1) * 256 + q * 64 + d, pv);
            }
        }
        // acc layout note: wgt row r = gt*2+e  ->  acc[gt*2+e]; gt stride 2.

        // ---- stage 5a: xp staging for token t+2 (slot (t+2)%3) ----
        if (wv == 1 && tn2 < L) {
            const int c = lane >> 4, off = (lane & 15) * 4;
            *(float4*)&xp_lds[tn2 % 3][c * 64 + off] =
                make_float4(xa.x+xb.x, xa.y+xb.y, xa.z+xb.z, xa.w+xb.w);
        }
        // ---- stage 5b: query for token t-1 (uses own hreg — no extra poll) ----
        if (q == 0 && wv == 2) {
            if (t >= 1) {
                const int b4 = lane >> 4;                  // 0..3
                const int k0 = 16 * (lane & 15) + 4 * b4;  // each k exactly once
                const float* eb = &emb_lds[(t - 1) & 1][0];
                float s0 = 0.f, s1 = 0.f;
                #pragma unroll
                for (int m = 0; m < 4; ++m) {
                    // static hreg indexing (runtime index would spill to scratch)
                    float hv = (b4 == 0) ? hreg[m] : (b4 == 1) ? hreg[4 + m]
                             : (b4 == 2) ? hreg[8 + m] : hreg[12 + m];
                    const int k = k0 + m;
                    float p = eb[k] * hv;
                    s0 = fmaf(p, wq_lds[0][k], s0);
                    s1 = fmaf(p, wq_lds[1][k], s1);
                }
                #pragma unroll
                for (int off2 = 32; off2; off2 >>= 1) {
                    s0 += __shfl_xor(s0, off2);
                    s1 += __shfl_xor(s1, off2);
                }
                if (lane == 0) {
                    const int tgt = act_s[t];     // actions[b, (t-1)+1]
                    float z0 = s0 + bq_lds[0], z1 = s1 + bq_lds[1];
                    float mz = fmaxf(z0, z1);
                    float lse = mz + __logf(__expf(z0 - mz) + __expf(z1 - mz));
                    nll_acc += lse - (tgt ? z1 : z0);
                    cnt_acc += 1.f;
                }
            }
            *(float4*)&emb_lds[t & 1][4 * lane] = ev;   // stage emb for query token t
        }

        // ---- single per-step barrier: orders LDS (xp triple-buffer, emb) only.
        // Cross-block h ordering is carried by the tags, not this barrier.
        step_barrier();
    }

    // ---- final token (query t = L-1 uses h^L); valid only when len==200 ----
    if (q == 0 && wv == 2) {
        if (items_s[L] != 0) {
            const int b4 = lane >> 4;
            const int k0 = 16 * (lane & 15) + 4 * b4;
            const u64* s2 = gbuf + (L & 1) * 256 + k0;
            u64 w[4];
            int guard = 0;
            for (;;) {
                #pragma unroll
                for (int m = 0; m < 4; ++m) w[m] = ld_pair(s2 + m);
                unsigned ok = 1u;
                #pragma unroll
                for (int m = 0; m < 4; ++m) ok &= (unsigned)((unsigned)w[m] == (unsigned)L);
                if (ok || ++guard > (1 << 16)) break;
            }
            const float* eb = &emb_lds[(L - 1) & 1][0];
            float s0 = 0.f, s1 = 0.f;
            #pragma unroll
            for (int m = 0; m < 4; ++m) {
                const int k = k0 + m;
                float p = eb[k] * __uint_as_float((unsigned)(w[m] >> 32));
                s0 = fmaf(p, wq_lds[0][k], s0);
                s1 = fmaf(p, wq_lds[1][k], s1);
            }
            #pragma unroll
            for (int off2 = 32; off2; off2 >>= 1) {
                s0 += __shfl_xor(s0, off2);
                s1 += __shfl_xor(s1, off2);
            }
            if (lane == 0) {
                const int tgt = act_s[L];
                float z0 = s0 + bq_lds[0], z1 = s1 + bq_lds[1];
                float mz = fmaxf(z0, z1);
                float lse = mz + __logf(__expf(z0 - mz) + __expf(z1 - mz));
                nll_acc += lse - (tgt ? z1 : z0);
                cnt_acc += 1.f;
            }
        }
        if (lane == 0) {
            atomicAdd(&accum[0], nll_acc);
            atomicAdd(&accum[1], cnt_acc);
        }
    }
}

__global__ void finalize_k(const float* __restrict__ accum, float* __restrict__ out) {
    out[0] = accum[0] / accum[1];
}

extern "C" void kernel_launch(void* const* d_in, const int* in_sizes, int n_in,
                              void* d_out, int out_size, void* d_ws, size_t ws_size,
                              hipStream_t stream)
{
    const int*   items     = (const int*)d_in[0];
    const int*   actions   = (const int*)d_in[1];
    const float* WihT      = (const float*)d_in[2];
    const float* Whh       = (const float*)d_in[3];
    const float* b_lstm    = (const float*)d_in[4];
    const float* trans_emb = (const float*)d_in[5];
    const float* Wq        = (const float*)d_in[6];
    const float* bq        = (const float*)d_in[7];

    char*  ws    = (char*)d_ws;
    float* accum = (float*)(ws + 8192);        // 8 B
    u64*   pairs = (u64*)(ws + 16384);         // 64*2*256*8 = 262144 B

    hipMemsetAsync(d_ws, 0, 16384 + 64 * 2 * 256 * 8, stream);

    lstm_main<<<dim3(256), dim3(512), 0, stream>>>(
        items, actions, WihT, Whh, b_lstm, trans_emb, Wq, bq, pairs, accum);
    finalize_k<<<dim3(1), dim3(1), 0, stream>>>(accum, (float*)d_out);
}